// Round 1
// baseline (16628.612 us; speedup 1.0000x reference)
//
#include <hip/hip_runtime.h>
#include <hip/hip_bf16.h>
#include <math.h>

// Problem constants (B=512, T=128, D=64, H=512, C=10)
#define B 512
#define T 128
#define D 64
#define H 512
#define NC 10
#define FOURH 2048           // 4*H
#define PRED_ROW 8128        // (T-1)*D
#define PRED_ELEMS 4161536   // B*(T-1)*D
#define MISSING_V 128.0f

// ---------------------------------------------------------------------------
// init: zero h0,h1,c0,c1 (4 * B*H floats, contiguous at ws[0]) and the
// loss_pred accumulator scalar.
// ---------------------------------------------------------------------------
__global__ __launch_bounds__(256) void init_zero(float* __restrict__ ws,
                                                 float* __restrict__ lp) {
    const int n4 = (4 * B * H) / 4;  // 262144 float4
    float4 z4 = make_float4(0.f, 0.f, 0.f, 0.f);
    for (int i = blockIdx.x * blockDim.x + threadIdx.x; i < n4;
         i += gridDim.x * blockDim.x) {
        ((float4*)ws)[i] = z4;
    }
    if (blockIdx.x == 0 && threadIdx.x == 0) *lp = 0.f;
}

// ---------------------------------------------------------------------------
// Two-segment fp32 GEMM:  C[M=512][N=2048] = [A1|A2] @ [B1;B2] + bias
//   A1: [512][K1] ld=lda1, A2: [512][K2] ld=lda2
//   B1: [K1][2048], B2: [K2][2048] (ld fixed 2048)
// Tile 64x64, BK=16, 256 threads, 4x4 per thread. Grid (32, 8) = 256 blocks.
// ---------------------------------------------------------------------------
#define BK 16
__global__ __launch_bounds__(256) void gemm2(
    const float* __restrict__ A1, int lda1, int K1,
    const float* __restrict__ A2, int lda2, int K2,
    const float* __restrict__ B1, const float* __restrict__ B2,
    const float* __restrict__ bias, float* __restrict__ C) {
    __shared__ float As[BK][68];   // padded: bank-spread + 16B-aligned rows
    __shared__ float Bs[BK][64];

    const int tid = threadIdx.x;
    const int row0 = blockIdx.y * 64;
    const int col0 = blockIdx.x * 64;

    // A-load mapping: one float4 per thread: row am, k-offset ak..ak+3
    const int am = tid >> 2;
    const int ak = (tid & 3) * 4;
    // B-load mapping: 4 rows per thread (bkr, bkr+4, bkr+8, bkr+12), col bcol
    const int bkr = tid >> 6;
    const int bcol = tid & 63;
    // compute mapping
    const int ty = tid >> 4;   // 0..15 -> rows ty*4..ty*4+3
    const int tx = tid & 15;   // 0..15 -> cols tx*4..tx*4+3

    float acc[4][4] = {};
    const int KT = K1 + K2;

    for (int k0 = 0; k0 < KT; k0 += BK) {
        // ---- stage A tile (transposed into LDS) ----
        const float* Ap; int lda; int kk;
        if (k0 < K1) { Ap = A1; lda = lda1; kk = k0; }
        else         { Ap = A2; lda = lda2; kk = k0 - K1; }
        float4 av = *(const float4*)(Ap + (size_t)(row0 + am) * lda + kk + ak);
        As[ak + 0][am] = av.x;
        As[ak + 1][am] = av.y;
        As[ak + 2][am] = av.z;
        As[ak + 3][am] = av.w;
        // ---- stage B tile ----
        const float* Bp = (k0 < K1) ? (B1 + (size_t)k0 * FOURH)
                                    : (B2 + (size_t)(k0 - K1) * FOURH);
#pragma unroll
        for (int j = 0; j < 4; ++j) {
            int kr = bkr + j * 4;
            Bs[kr][bcol] = Bp[(size_t)kr * FOURH + col0 + bcol];
        }
        __syncthreads();
        // ---- compute ----
#pragma unroll
        for (int k = 0; k < BK; ++k) {
            float4 a4 = *(const float4*)&As[k][ty * 4];
            float4 b4 = *(const float4*)&Bs[k][tx * 4];
            acc[0][0] += a4.x * b4.x; acc[0][1] += a4.x * b4.y;
            acc[0][2] += a4.x * b4.z; acc[0][3] += a4.x * b4.w;
            acc[1][0] += a4.y * b4.x; acc[1][1] += a4.y * b4.y;
            acc[1][2] += a4.y * b4.z; acc[1][3] += a4.y * b4.w;
            acc[2][0] += a4.z * b4.x; acc[2][1] += a4.z * b4.y;
            acc[2][2] += a4.z * b4.z; acc[2][3] += a4.z * b4.w;
            acc[3][0] += a4.w * b4.x; acc[3][1] += a4.w * b4.y;
            acc[3][2] += a4.w * b4.z; acc[3][3] += a4.w * b4.w;
        }
        __syncthreads();
    }

    const int crow = row0 + ty * 4;
    const int ccol = col0 + tx * 4;
    float4 bs = *(const float4*)&bias[ccol];
#pragma unroll
    for (int i = 0; i < 4; ++i) {
        float4 v;
        v.x = acc[i][0] + bs.x;
        v.y = acc[i][1] + bs.y;
        v.z = acc[i][2] + bs.z;
        v.w = acc[i][3] + bs.w;
        *(float4*)&C[(size_t)(crow + i) * FOURH + ccol] = v;
    }
}

// ---------------------------------------------------------------------------
// LSTM cell elementwise: gates i,f,g,o from z[B][4H]; updates c, h in place.
// ---------------------------------------------------------------------------
__device__ __forceinline__ float sigmoidf_(float x) {
    return 1.0f / (1.0f + expf(-x));
}

__global__ __launch_bounds__(256) void lstm_cell(const float* __restrict__ z,
                                                 float* __restrict__ cst,
                                                 float* __restrict__ h) {
    int idx = blockIdx.x * blockDim.x + threadIdx.x;  // 0 .. B*H-1
    int b = idx >> 9;          // /512
    int j = idx & (H - 1);
    const float* zr = z + (size_t)b * FOURH;
    float gi = zr[j];
    float gf = zr[H + j];
    float gg = zr[2 * H + j];
    float go = zr[3 * H + j];
    float c_old = cst[idx];
    float c_new = sigmoidf_(gf) * c_old + sigmoidf_(gi) * tanhf(gg);
    float h_new = sigmoidf_(go) * tanhf(c_new);
    cst[idx] = c_new;
    h[idx] = h_new;
}

// ---------------------------------------------------------------------------
// pred = h1_prev @ W + b  (written straight into prediction output row t-1),
// cur  = where(x_t == MISSING, pred, x_t)
// Block = 256 threads = 4 rows x 64 cols. 128 blocks.
// ---------------------------------------------------------------------------
__global__ __launch_bounds__(256) void pred_impute(
    const float* __restrict__ h1, const float* __restrict__ W,
    const float* __restrict__ bvec, const float* __restrict__ x_t,
    float* __restrict__ pred_out, float* __restrict__ cur) {
    __shared__ float h1s[4 * H];
    const int tid = threadIdx.x;
    const int rowbase = blockIdx.x * 4;
    // stage 4 rows of h1 (contiguous 2048 floats)
    const float4* src = (const float4*)(h1 + (size_t)rowbase * H);
    float4* dst = (float4*)h1s;
    dst[tid] = src[tid];
    dst[tid + 256] = src[tid + 256];
    __syncthreads();

    const int r = tid >> 6;
    const int c = tid & 63;
    const float* hr = h1s + r * H;
    float acc = 0.f;
#pragma unroll 4
    for (int k = 0; k < H; k += 4) {
        float4 hv = *(const float4*)&hr[k];
        acc += hv.x * W[(k + 0) * D + c];
        acc += hv.y * W[(k + 1) * D + c];
        acc += hv.z * W[(k + 2) * D + c];
        acc += hv.w * W[(k + 3) * D + c];
    }
    acc += bvec[c];
    const int row = rowbase + r;
    pred_out[(size_t)row * PRED_ROW + c] = acc;
    float xv = x_t[(size_t)row * (T * D) + c];
    cur[row * D + c] = (xv == MISSING_V) ? acc : xv;
}

// ---------------------------------------------------------------------------
// Fused: M output copy + masked-squared-error reduction into *accum.
// ---------------------------------------------------------------------------
__global__ __launch_bounds__(256) void pred_loss_reduce(
    const float* __restrict__ pred, const float* __restrict__ targ,
    const float* __restrict__ mask, float* __restrict__ Mout,
    float* __restrict__ accum) {
    const int n4 = PRED_ELEMS / 4;
    float part = 0.f;
    for (int i = blockIdx.x * blockDim.x + threadIdx.x; i < n4;
         i += gridDim.x * blockDim.x) {
        float4 p = ((const float4*)pred)[i];
        float4 t = ((const float4*)targ)[i];
        float4 m = ((const float4*)mask)[i];
        ((float4*)Mout)[i] = m;
        float dx = (t.x - p.x) * m.x;
        float dy = (t.y - p.y) * m.y;
        float dz = (t.z - p.z) * m.z;
        float dw = (t.w - p.w) * m.w;
        part += dx * dx + dy * dy + dz * dz + dw * dw;
    }
    // wave64 reduce
#pragma unroll
    for (int off = 32; off > 0; off >>= 1) part += __shfl_down(part, off, 64);
    __shared__ float wsum[4];
    int lane = threadIdx.x & 63, wid = threadIdx.x >> 6;
    if (lane == 0) wsum[wid] = part;
    __syncthreads();
    if (threadIdx.x == 0) {
        atomicAdd(accum, wsum[0] + wsum[1] + wsum[2] + wsum[3]);
    }
}

// ---------------------------------------------------------------------------
// Final: logits = h1_last @ Wc + bc; log-softmax class loss; accuracy;
// loss[b] = loss_class[b] + loss_pred_scalar. One block (64 lanes) per b.
// ---------------------------------------------------------------------------
__global__ __launch_bounds__(64) void final_loss(
    const float* __restrict__ h1, const float* __restrict__ Wc,
    const float* __restrict__ bc, const float* __restrict__ label,
    const float* __restrict__ lp_accum, float* __restrict__ loss,
    float* __restrict__ acc_out) {
    const int b = blockIdx.x;
    const int lane = threadIdx.x;
    float partial[NC];
#pragma unroll
    for (int c = 0; c < NC; ++c) partial[c] = 0.f;
    for (int k = lane; k < H; k += 64) {
        float hv = h1[(size_t)b * H + k];
#pragma unroll
        for (int c = 0; c < NC; ++c) partial[c] += hv * Wc[k * NC + c];
    }
    float logits[NC];
#pragma unroll
    for (int c = 0; c < NC; ++c) {
        float v = partial[c];
#pragma unroll
        for (int off = 32; off > 0; off >>= 1) v += __shfl_down(v, off, 64);
        logits[c] = v + bc[c];
    }
    if (lane == 0) {
        float mx = logits[0];
#pragma unroll
        for (int c = 1; c < NC; ++c) mx = fmaxf(mx, logits[c]);
        float se = 0.f;
#pragma unroll
        for (int c = 0; c < NC; ++c) se += expf(logits[c] - mx);
        float lse = logf(se);
        float lcls = 0.f;
        int am_p = 0, am_l = 0;
        float bp = logits[0], bl = label[(size_t)b * NC];
#pragma unroll
        for (int c = 0; c < NC; ++c) {
            float lt = label[(size_t)b * NC + c];
            lcls -= lt * (logits[c] - mx - lse);
            if (c > 0) {
                if (logits[c] > bp) { bp = logits[c]; am_p = c; }
                if (lt > bl) { bl = lt; am_l = c; }
            }
        }
        float lp = lp_accum[0] * (1.0f / (float)PRED_ELEMS) * (1.0f / (float)B);
        loss[b] = lcls + lp;
        acc_out[b] = (am_p == am_l) ? 1.f : 0.f;
    }
}

// ---------------------------------------------------------------------------
extern "C" void kernel_launch(void* const* d_in, const int* in_sizes, int n_in,
                              void* d_out, int out_size, void* d_ws,
                              size_t ws_size, hipStream_t stream) {
    const float* inputs  = (const float*)d_in[0];   // [B][T][D]
    const float* ptarget = (const float*)d_in[1];   // [B][T-1][D]
    const float* mask    = (const float*)d_in[2];   // [B][T-1][D]
    const float* label   = (const float*)d_in[3];   // [B][C]
    const float* W       = (const float*)d_in[4];   // [H][D]
    const float* bvec    = (const float*)d_in[5];   // [D]
    const float* k0      = (const float*)d_in[6];   // [D][4H]
    const float* r0      = (const float*)d_in[7];   // [H][4H]
    const float* b0      = (const float*)d_in[8];   // [4H]
    const float* k1      = (const float*)d_in[9];   // [H][4H]
    const float* r1      = (const float*)d_in[10];  // [H][4H]
    const float* b1      = (const float*)d_in[11];  // [4H]
    const float* Wc      = (const float*)d_in[12];  // [H][C]
    const float* bc      = (const float*)d_in[13];  // [C]

    float* out = (float*)d_out;
    float* loss    = out;
    float* predout = out + B;
    float* Mout    = out + B + PRED_ELEMS;
    float* accout  = out + B + 2 * (size_t)PRED_ELEMS;

    float* ws = (float*)d_ws;
    float* h0  = ws;                  // [B][H]
    float* h1  = ws + 1 * B * H;      // [B][H]
    float* c0  = ws + 2 * B * H;      // [B][H]
    float* c1  = ws + 3 * B * H;      // [B][H]
    float* cur = ws + 4 * B * H;      // [B][D]
    float* z   = cur + B * D;         // [B][4H]
    float* lp  = z + (size_t)B * FOURH;  // scalar

    init_zero<<<512, 256, 0, stream>>>(ws, lp);

    dim3 ggrid(FOURH / 64, B / 64);  // (32, 8)

    // ---- t = 0: no imputation; h/c start at zero ----
    gemm2<<<ggrid, 256, 0, stream>>>(inputs, T * D, D, h0, H, H, k0, r0, b0, z);
    lstm_cell<<<(B * H) / 256, 256, 0, stream>>>(z, c0, h0);
    gemm2<<<ggrid, 256, 0, stream>>>(h0, H, H, h1, H, H, k1, r1, b1, z);
    lstm_cell<<<(B * H) / 256, 256, 0, stream>>>(z, c1, h1);

    // ---- t = 1 .. 127 ----
    for (int t = 1; t < T; ++t) {
        pred_impute<<<B / 4, 256, 0, stream>>>(h1, W, bvec, inputs + t * D,
                                               predout + (t - 1) * D, cur);
        gemm2<<<ggrid, 256, 0, stream>>>(cur, D, D, h0, H, H, k0, r0, b0, z);
        lstm_cell<<<(B * H) / 256, 256, 0, stream>>>(z, c0, h0);
        gemm2<<<ggrid, 256, 0, stream>>>(h0, H, H, h1, H, H, k1, r1, b1, z);
        lstm_cell<<<(B * H) / 256, 256, 0, stream>>>(z, c1, h1);
    }

    // ---- epilogue ----
    pred_loss_reduce<<<1024, 256, 0, stream>>>(predout, ptarget, mask, Mout, lp);
    final_loss<<<B, 64, 0, stream>>>(h1, Wc, bc, label, lp, loss, accout);
}

// Round 2
// 11660.260 us; speedup vs baseline: 1.4261x; 1.4261x over previous
//
#include <hip/hip_runtime.h>
#include <hip/hip_bf16.h>
#include <math.h>

// Problem constants (B=512, T=128, D=64, H=512, C=10)
#define B 512
#define T 128
#define D 64
#define H 512
#define NC 10
#define FOURH 2048           // 4*H
#define PRED_ROW 8128        // (T-1)*D
#define PRED_ELEMS 4161536   // B*(T-1)*D
#define MISSING_V 128.0f
#define K0TOT 576            // D + H
#define K1TOT 1024           // H + H
#define BH (B * H)

// GEMM tile geometry: 32 rows x 128 ncols (=32 h-units x 4 gates), BK=32,
// 512 threads (8 waves) -> grid (2048/128, 512/32) = (16,16) = 256 blocks
// = 1 block/CU, 2 waves/SIMD.
#define BM 32
#define BN 128
#define BKK 32

__device__ __forceinline__ float sigm(float x) {
    return 1.0f / (1.0f + __expf(-x));
}

// ---------------------------------------------------------------------------
// One-time weight reorder into gate-interleaved layout:
//   Wr0[r][h*4+g] = {k0|r0}[r][g*H+h]   (r < 64 -> k0, else r0)
//   Wr1[r][h*4+g] = {k1|r1}[r][g*H+h]
//   br*[h*4+g]    = b*[g*H+h]
// ---------------------------------------------------------------------------
__global__ __launch_bounds__(256) void reorder_weights(
    const float* __restrict__ k0, const float* __restrict__ r0,
    const float* __restrict__ b0, const float* __restrict__ k1,
    const float* __restrict__ r1, const float* __restrict__ b1,
    float* __restrict__ Wr0, float* __restrict__ br0,
    float* __restrict__ Wr1, float* __restrict__ br1) {
    const int n0 = K0TOT * FOURH;
    const int n1 = K1TOT * FOURH;
    const int total = n0 + n1 + 2 * FOURH;
    for (int idx = blockIdx.x * blockDim.x + threadIdx.x; idx < total;
         idx += gridDim.x * blockDim.x) {
        if (idx < n0) {
            int r = idx >> 11, n = idx & 2047;
            int src = (n & 3) * H + (n >> 2);
            Wr0[idx] = (r < D) ? k0[r * FOURH + src] : r0[(r - D) * FOURH + src];
        } else if (idx < n0 + n1) {
            int j = idx - n0;
            int r = j >> 11, n = j & 2047;
            int src = (n & 3) * H + (n >> 2);
            Wr1[j] = (r < H) ? k1[r * FOURH + src] : r1[(r - H) * FOURH + src];
        } else {
            int j = idx - n0 - n1;
            if (j < FOURH) {
                br0[j] = b0[(j & 3) * H + (j >> 2)];
            } else {
                int j2 = j - FOURH;
                br1[j2] = b1[(j2 & 3) * H + (j2 >> 2)];
            }
        }
    }
}

// ---------------------------------------------------------------------------
// init: zero h0a,h1a,c0,c1 (first 4*B*H floats of ws) and loss accumulator.
// ---------------------------------------------------------------------------
__global__ __launch_bounds__(256) void init_zero(float* __restrict__ ws,
                                                 float* __restrict__ lp) {
    const int n4 = (4 * BH) / 4;
    float4 z4 = make_float4(0.f, 0.f, 0.f, 0.f);
    for (int i = blockIdx.x * blockDim.x + threadIdx.x; i < n4;
         i += gridDim.x * blockDim.x) {
        ((float4*)ws)[i] = z4;
    }
    if (blockIdx.x == 0 && threadIdx.x == 0) *lp = 0.f;
}

// ---------------------------------------------------------------------------
// Fused GEMM + LSTM cell.
//   z[512][2048'] = [A1|A2] @ Wr + br   (gate-interleaved N)
//   per h-unit: c_new = sig(f)*c_old + sig(i)*tanh(g); h = sig(o)*tanh(c_new)
// Double-buffered LDS, single barrier/iter, split staging (loads before
// compute, LDS writes after) so global latency hides under the FMA phase.
// Thread (tx=tid&31, ty=tid>>5): rows row0+ty*2+{0,1}, ncols n0+tx*4..+3
// = gates i,f,g,o of h-unit hc = n0/4 + tx  -> in-register cell epilogue.
// ---------------------------------------------------------------------------
__global__ __launch_bounds__(512) void gemm_cell(
    const float* __restrict__ A1, int lda1, int K1,
    const float* __restrict__ A2, int lda2, int KT,
    const float* __restrict__ Wr, const float* __restrict__ br,
    const float* __restrict__ c_in, float* __restrict__ c_out,
    float* __restrict__ h_out) {
    __shared__ float As[2][BKK][34];    // transposed, pad 34: write 2-way (free), read broadcast
    __shared__ float Bs[2][BKK][132];   // pad 132: conflict-free b128 read/write
    const int tid = threadIdx.x;
    const int row0 = blockIdx.y * BM;
    const int n0 = blockIdx.x * BN;
    const int nIter = KT / BKK;

    // staging maps
    const int ar = tid >> 4;            // A row in tile (0..31)
    const int ak = (tid & 15) * 2;      // A k-pair
    const int brr = tid >> 4;           // B row in tile (0..31)
    const int bc8 = (tid & 15) * 8;     // B col offset (2x float4)
    // compute map
    const int tx = tid & 31;
    const int ty = tid >> 5;            // 0..15

    float acc00 = 0, acc01 = 0, acc02 = 0, acc03 = 0;
    float acc10 = 0, acc11 = 0, acc12 = 0, acc13 = 0;

    // prologue: stage tile 0 (tile 0 always inside segment A1: K1 >= BKK)
    {
        float2 av = *(const float2*)(A1 + (size_t)(row0 + ar) * lda1 + ak);
        const float* Bp = Wr + (size_t)brr * FOURH + n0 + bc8;
        float4 bv0 = *(const float4*)Bp;
        float4 bv1 = *(const float4*)(Bp + 4);
        As[0][ak][ar] = av.x;
        As[0][ak + 1][ar] = av.y;
        *(float4*)&Bs[0][brr][bc8] = bv0;
        *(float4*)&Bs[0][brr][bc8 + 4] = bv1;
    }

    for (int it = 0; it < nIter; ++it) {
        __syncthreads();   // buf[it&1] staged; prior reads of buf[it&1^1] done
        const int buf = it & 1;
        float2 av;
        float4 bv0, bv1;
        const bool more = (it + 1 < nIter);
        if (more) {        // issue global loads early (hide under compute)
            const int k0n = (it + 1) * BKK;
            const float* Ap;
            int lda, kk;
            if (k0n < K1) { Ap = A1; lda = lda1; kk = k0n; }
            else          { Ap = A2; lda = lda2; kk = k0n - K1; }
            av = *(const float2*)(Ap + (size_t)(row0 + ar) * lda + kk + ak);
            const float* Bp = Wr + (size_t)(k0n + brr) * FOURH + n0 + bc8;
            bv0 = *(const float4*)Bp;
            bv1 = *(const float4*)(Bp + 4);
        }
#pragma unroll
        for (int k = 0; k < BKK; ++k) {
            float2 a2 = *(const float2*)&As[buf][k][ty * 2];
            float4 b4 = *(const float4*)&Bs[buf][k][tx * 4];
            acc00 += a2.x * b4.x; acc01 += a2.x * b4.y;
            acc02 += a2.x * b4.z; acc03 += a2.x * b4.w;
            acc10 += a2.y * b4.x; acc11 += a2.y * b4.y;
            acc12 += a2.y * b4.z; acc13 += a2.y * b4.w;
        }
        if (more) {        // LDS writes after compute (waits only on own loads)
            const int nb = buf ^ 1;
            As[nb][ak][ar] = av.x;
            As[nb][ak + 1][ar] = av.y;
            *(float4*)&Bs[nb][brr][bc8] = bv0;
            *(float4*)&Bs[nb][brr][bc8 + 4] = bv1;
        }
    }

    // ---- fused cell epilogue (gates are this thread's 4 acc columns) ----
    const int hc = (n0 >> 2) + tx;
    float4 bb = *(const float4*)&br[n0 + tx * 4];
    {
        int row = row0 + ty * 2;
        float gi = acc00 + bb.x, gf = acc01 + bb.y;
        float gg = acc02 + bb.z, go = acc03 + bb.w;
        float c_old = c_in[(size_t)row * H + hc];
        float cn = sigm(gf) * c_old + sigm(gi) * tanhf(gg);
        c_out[(size_t)row * H + hc] = cn;
        h_out[(size_t)row * H + hc] = sigm(go) * tanhf(cn);
    }
    {
        int row = row0 + ty * 2 + 1;
        float gi = acc10 + bb.x, gf = acc11 + bb.y;
        float gg = acc12 + bb.z, go = acc13 + bb.w;
        float c_old = c_in[(size_t)row * H + hc];
        float cn = sigm(gf) * c_old + sigm(gi) * tanhf(gg);
        c_out[(size_t)row * H + hc] = cn;
        h_out[(size_t)row * H + hc] = sigm(go) * tanhf(cn);
    }
}

// ---------------------------------------------------------------------------
// pred = h1_prev @ W + b (written straight into prediction output row t-1),
// cur = where(x_t == MISSING, pred, x_t). 128 blocks x 256 threads.
// ---------------------------------------------------------------------------
__global__ __launch_bounds__(256) void pred_impute(
    const float* __restrict__ h1, const float* __restrict__ W,
    const float* __restrict__ bvec, const float* __restrict__ x_t,
    float* __restrict__ pred_out, float* __restrict__ cur) {
    __shared__ float h1s[4 * H];
    const int tid = threadIdx.x;
    const int rowbase = blockIdx.x * 4;
    const float4* src = (const float4*)(h1 + (size_t)rowbase * H);
    float4* dst = (float4*)h1s;
    dst[tid] = src[tid];
    dst[tid + 256] = src[tid + 256];
    __syncthreads();

    const int r = tid >> 6;
    const int c = tid & 63;
    const float* hr = h1s + r * H;
    float acc = 0.f;
#pragma unroll 4
    for (int k = 0; k < H; k += 4) {
        float4 hv = *(const float4*)&hr[k];
        acc += hv.x * W[(k + 0) * D + c];
        acc += hv.y * W[(k + 1) * D + c];
        acc += hv.z * W[(k + 2) * D + c];
        acc += hv.w * W[(k + 3) * D + c];
    }
    acc += bvec[c];
    const int row = rowbase + r;
    pred_out[(size_t)row * PRED_ROW + c] = acc;
    float xv = x_t[(size_t)row * (T * D) + c];
    cur[row * D + c] = (xv == MISSING_V) ? acc : xv;
}

// ---------------------------------------------------------------------------
// Fused: M output copy + masked-squared-error reduction into *accum.
// ---------------------------------------------------------------------------
__global__ __launch_bounds__(256) void pred_loss_reduce(
    const float* __restrict__ pred, const float* __restrict__ targ,
    const float* __restrict__ mask, float* __restrict__ Mout,
    float* __restrict__ accum) {
    const int n4 = PRED_ELEMS / 4;
    float part = 0.f;
    for (int i = blockIdx.x * blockDim.x + threadIdx.x; i < n4;
         i += gridDim.x * blockDim.x) {
        float4 p = ((const float4*)pred)[i];
        float4 t = ((const float4*)targ)[i];
        float4 m = ((const float4*)mask)[i];
        ((float4*)Mout)[i] = m;
        float dx = (t.x - p.x) * m.x;
        float dy = (t.y - p.y) * m.y;
        float dz = (t.z - p.z) * m.z;
        float dw = (t.w - p.w) * m.w;
        part += dx * dx + dy * dy + dz * dz + dw * dw;
    }
#pragma unroll
    for (int off = 32; off > 0; off >>= 1) part += __shfl_down(part, off, 64);
    __shared__ float wsum[4];
    int lane = threadIdx.x & 63, wid = threadIdx.x >> 6;
    if (lane == 0) wsum[wid] = part;
    __syncthreads();
    if (threadIdx.x == 0) {
        atomicAdd(accum, wsum[0] + wsum[1] + wsum[2] + wsum[3]);
    }
}

// ---------------------------------------------------------------------------
// Final: logits = h1_last @ Wc + bc; log-softmax loss; accuracy.
// ---------------------------------------------------------------------------
__global__ __launch_bounds__(64) void final_loss(
    const float* __restrict__ h1, const float* __restrict__ Wc,
    const float* __restrict__ bc, const float* __restrict__ label,
    const float* __restrict__ lp_accum, float* __restrict__ loss,
    float* __restrict__ acc_out) {
    const int b = blockIdx.x;
    const int lane = threadIdx.x;
    float partial[NC];
#pragma unroll
    for (int c = 0; c < NC; ++c) partial[c] = 0.f;
    for (int k = lane; k < H; k += 64) {
        float hv = h1[(size_t)b * H + k];
#pragma unroll
        for (int c = 0; c < NC; ++c) partial[c] += hv * Wc[k * NC + c];
    }
    float logits[NC];
#pragma unroll
    for (int c = 0; c < NC; ++c) {
        float v = partial[c];
#pragma unroll
        for (int off = 32; off > 0; off >>= 1) v += __shfl_down(v, off, 64);
        logits[c] = v + bc[c];
    }
    if (lane == 0) {
        float mx = logits[0];
#pragma unroll
        for (int c = 1; c < NC; ++c) mx = fmaxf(mx, logits[c]);
        float se = 0.f;
#pragma unroll
        for (int c = 0; c < NC; ++c) se += expf(logits[c] - mx);
        float lse = logf(se);
        float lcls = 0.f;
        int am_p = 0, am_l = 0;
        float bp = logits[0], bl = label[(size_t)b * NC];
#pragma unroll
        for (int c = 0; c < NC; ++c) {
            float lt = label[(size_t)b * NC + c];
            lcls -= lt * (logits[c] - mx - lse);
            if (c > 0) {
                if (logits[c] > bp) { bp = logits[c]; am_p = c; }
                if (lt > bl) { bl = lt; am_l = c; }
            }
        }
        float lp = lp_accum[0] * (1.0f / (float)PRED_ELEMS) * (1.0f / (float)B);
        loss[b] = lcls + lp;
        acc_out[b] = (am_p == am_l) ? 1.f : 0.f;
    }
}

// ---------------------------------------------------------------------------
extern "C" void kernel_launch(void* const* d_in, const int* in_sizes, int n_in,
                              void* d_out, int out_size, void* d_ws,
                              size_t ws_size, hipStream_t stream) {
    const float* inputs  = (const float*)d_in[0];   // [B][T][D]
    const float* ptarget = (const float*)d_in[1];   // [B][T-1][D]
    const float* mask    = (const float*)d_in[2];   // [B][T-1][D]
    const float* label   = (const float*)d_in[3];   // [B][C]
    const float* W       = (const float*)d_in[4];   // [H][D]
    const float* bvec    = (const float*)d_in[5];   // [D]
    const float* k0      = (const float*)d_in[6];   // [D][4H]
    const float* r0      = (const float*)d_in[7];   // [H][4H]
    const float* b0      = (const float*)d_in[8];   // [4H]
    const float* k1      = (const float*)d_in[9];   // [H][4H]
    const float* r1      = (const float*)d_in[10];  // [H][4H]
    const float* b1      = (const float*)d_in[11];  // [4H]
    const float* Wc      = (const float*)d_in[12];  // [H][C]
    const float* bc      = (const float*)d_in[13];  // [C]

    float* out = (float*)d_out;
    float* loss    = out;
    float* predout = out + B;
    float* Mout    = out + B + PRED_ELEMS;
    float* accout  = out + B + 2 * (size_t)PRED_ELEMS;

    float* ws = (float*)d_ws;
    float* h0a = ws;                    // zeroed
    float* h1a = ws + (size_t)BH;       // zeroed
    float* c0  = ws + 2 * (size_t)BH;   // zeroed
    float* c1  = ws + 3 * (size_t)BH;   // zeroed
    float* h0b = ws + 4 * (size_t)BH;
    float* h1b = ws + 5 * (size_t)BH;
    float* cur = ws + 6 * (size_t)BH;          // [B][D]
    float* Wr0 = cur + B * D;                  // [576][2048]
    float* br0 = Wr0 + (size_t)K0TOT * FOURH;  // [2048]
    float* Wr1 = br0 + FOURH;                  // [1024][2048]
    float* br1 = Wr1 + (size_t)K1TOT * FOURH;  // [2048]
    float* lp  = br1 + FOURH;                  // scalar

    reorder_weights<<<2048, 256, 0, stream>>>(k0, r0, b0, k1, r1, b1,
                                              Wr0, br0, Wr1, br1);
    init_zero<<<512, 256, 0, stream>>>(ws, lp);

    dim3 gg(FOURH / BN, B / BM);  // (16,16)

    // ---- t = 0: raw input, zero states ----
    gemm_cell<<<gg, 512, 0, stream>>>(inputs, T * D, D, h0a, H, K0TOT,
                                      Wr0, br0, c0, c0, h0b);
    gemm_cell<<<gg, 512, 0, stream>>>(h0b, H, H, h1a, H, K1TOT,
                                      Wr1, br1, c1, c1, h1b);
    float* h0_cur = h0b; float* h0_alt = h0a;
    float* h1_cur = h1b; float* h1_alt = h1a;

    // ---- t = 1 .. 127 ----
    for (int t = 1; t < T; ++t) {
        pred_impute<<<B / 4, 256, 0, stream>>>(h1_cur, W, bvec, inputs + t * D,
                                               predout + (size_t)(t - 1) * D, cur);
        gemm_cell<<<gg, 512, 0, stream>>>(cur, D, D, h0_cur, H, K0TOT,
                                          Wr0, br0, c0, c0, h0_alt);
        gemm_cell<<<gg, 512, 0, stream>>>(h0_alt, H, H, h1_cur, H, K1TOT,
                                          Wr1, br1, c1, c1, h1_alt);
        float* tmp = h0_cur; h0_cur = h0_alt; h0_alt = tmp;
        tmp = h1_cur; h1_cur = h1_alt; h1_alt = tmp;
    }

    // ---- epilogue ----
    pred_loss_reduce<<<1024, 256, 0, stream>>>(predout, ptarget, mask, Mout, lp);
    final_loss<<<B, 64, 0, stream>>>(h1_cur, Wc, bc, label, lp, loss, accout);
}

// Round 3
// 7103.515 us; speedup vs baseline: 2.3409x; 1.6415x over previous
//
#include <hip/hip_runtime.h>
#include <hip/hip_bf16.h>
#include <math.h>

// Problem constants (B=512, T=128, D=64, H=512, C=10)
#define B 512
#define T 128
#define D 64
#define H 512
#define NC 10
#define FOURH 2048
#define PRED_ROW 8128        // (T-1)*D
#define PRED_ELEMS 4161536   // B*(T-1)*D
#define MISSING_V 128.0f
#define K0TOT 576            // D + H   -> 18 chunks of 32
#define K1TOT 1024           // H + H   -> 32 chunks of 32
#define KC0 18
#define KC1 32
#define BH (B * H)

typedef __attribute__((ext_vector_type(8))) short bf16x8;
typedef __attribute__((ext_vector_type(4))) float f32x4;

__device__ __forceinline__ float sigm(float x) {
    return 1.0f / (1.0f + __expf(-x));
}
__device__ __forceinline__ ushort f2bf(float x) {
    __hip_bfloat16 h = __float2bfloat16(x);   // RNE
    return *(ushort*)&h;
}
__device__ __forceinline__ float bf2f(ushort u) {
    __hip_bfloat16 h;
    *(ushort*)&h = u;
    return __bfloat162float(h);
}

// ---------------------------------------------------------------------------
// Weight pack: B-fragment-direct layout, hi/lo split.
// Element (k, n) of layer L (K = 576 or 1024, KCt = K/32):
//   ct = n>>4, kc = k>>5, sub = (k>>3)&3, c = n&15, j = k&7
//   idx = (((ct*KCt + kc)*4 + sub)*16 + c)*8 + j
// Source: cols n = g*H + h (original gate-major); rows = [k-weights ; r-weights].
// ---------------------------------------------------------------------------
__global__ __launch_bounds__(256) void pack_weights(
    const float* __restrict__ k0, const float* __restrict__ r0,
    const float* __restrict__ k1, const float* __restrict__ r1,
    ushort* __restrict__ Bhi0, ushort* __restrict__ Blo0,
    ushort* __restrict__ Bhi1, ushort* __restrict__ Blo1) {
    const int n0 = K0TOT * FOURH;
    const int n1 = K1TOT * FOURH;
    for (int idx = blockIdx.x * blockDim.x + threadIdx.x; idx < n0 + n1;
         idx += gridDim.x * blockDim.x) {
        float v;
        ushort* dhi;
        ushort* dlo;
        size_t didx;
        if (idx < n0) {
            int k = idx >> 11, n = idx & 2047;
            v = (k < D) ? k0[k * FOURH + n] : r0[(k - D) * FOURH + n];
            int ct = n >> 4, kc = k >> 5, sub = (k >> 3) & 3, c = n & 15, j = k & 7;
            didx = ((((size_t)ct * KC0 + kc) * 4 + sub) * 16 + c) * 8 + j;
            dhi = Bhi0; dlo = Blo0;
        } else {
            int i2 = idx - n0;
            int k = i2 >> 11, n = i2 & 2047;
            v = (k < H) ? k1[k * FOURH + n] : r1[(k - H) * FOURH + n];
            int ct = n >> 4, kc = k >> 5, sub = (k >> 3) & 3, c = n & 15, j = k & 7;
            didx = ((((size_t)ct * KC1 + kc) * 4 + sub) * 16 + c) * 8 + j;
            dhi = Bhi1; dlo = Blo1;
        }
        ushort hb = f2bf(v);
        dhi[didx] = hb;
        dlo[didx] = f2bf(v - bf2f(hb));
    }
}

// ---------------------------------------------------------------------------
// Zero the state region (c0,c1,h0hiA,h0loA,h1hiA,h1loA,lp) — contiguous.
// ---------------------------------------------------------------------------
__global__ __launch_bounds__(256) void init_zero(float4* __restrict__ z, int n4) {
    for (int i = blockIdx.x * blockDim.x + threadIdx.x; i < n4;
         i += gridDim.x * blockDim.x)
        z[i] = make_float4(0.f, 0.f, 0.f, 0.f);
}

// ---------------------------------------------------------------------------
// Pack x(:,0,:) into A-fragment layout hi/lo: elem (row,c):
//   idx = ((c>>3)*512 + row)*8 + (c&7)
// ---------------------------------------------------------------------------
__global__ __launch_bounds__(256) void pack_x0(const float* __restrict__ inputs,
                                               ushort* __restrict__ xhi,
                                               ushort* __restrict__ xlo) {
    int idx = blockIdx.x * blockDim.x + threadIdx.x;  // 0..32767
    int row = idx >> 6, c = idx & 63;
    float v = inputs[(size_t)row * (T * D) + c];
    ushort hb = f2bf(v);
    size_t po = ((size_t)(c >> 3) * 512 + row) * 8 + (c & 7);
    xhi[po] = hb;
    xlo[po] = f2bf(v - bf2f(hb));
}

// ---------------------------------------------------------------------------
// Fused MFMA GEMM + LSTM cell.  z = [A1|A2] @ W + b, then cell nonlinearity.
// 3-pass bf16 hi/lo split: hh + hl + lh accumulated in fp32 MFMA.
// Grid: 256 blocks = 8 rowblocks(64 r) x 32 hblocks(16 h), XCD-grouped by hb.
// Block: 8 waves = 4 row-subtiles(16 r) x 2 K-halves; LDS reduce at end.
// Wave tile: 16 r x 16 h x 4 gates = 4 accumulators; all operands are
// fragment-direct 16B/lane global loads (L2-resident), NO staging barriers.
// ---------------------------------------------------------------------------
__global__ __launch_bounds__(512) void gemm_cell_mfma(
    const ushort* __restrict__ Ahi1, const ushort* __restrict__ Alo1, int KCseg1,
    const ushort* __restrict__ Ahi2, const ushort* __restrict__ Alo2,
    const ushort* __restrict__ Bhi, const ushort* __restrict__ Blo,
    int KCt, int nHalf,
    const float* __restrict__ bias, float* __restrict__ cst,
    ushort* __restrict__ h_hi, ushort* __restrict__ h_lo,
    float* __restrict__ h_f32) {
    __shared__ float red[4][4][64][4];  // 16 KB: [wrow][gate][lane][reg]

    const int bid = blockIdx.x;
    const int xcd = bid & 7;
    const int wi = bid >> 3;
    const int rb = wi >> 2;             // 0..7
    const int hb = xcd * 4 + (wi & 3);  // 0..31
    const int tid = threadIdx.x;
    const int wid = tid >> 6;
    const int l = tid & 63;
    const int wrow = wid & 3;
    const int ks = wid >> 2;            // K-half
    const int c16 = l & 15;
    const int sub = l >> 4;             // k-subgroup 0..3
    const int rowbase = rb * 64 + wrow * 16;
    const int arow = rowbase + c16;     // A-fragment row

    f32x4 acc0 = {0.f, 0.f, 0.f, 0.f};
    f32x4 acc1 = {0.f, 0.f, 0.f, 0.f};
    f32x4 acc2 = {0.f, 0.f, 0.f, 0.f};
    f32x4 acc3 = {0.f, 0.f, 0.f, 0.f};

    const int kcS = ks * nHalf;
    const int kcE = kcS + nHalf;

    // B fragment pointers (advance 512 ushorts per k-chunk)
    size_t bb0 = ((size_t)(0 * 32 + hb) * KCt + kcS) * 512 + sub * 128 + c16 * 8;
    size_t bb1 = ((size_t)(1 * 32 + hb) * KCt + kcS) * 512 + sub * 128 + c16 * 8;
    size_t bb2 = ((size_t)(2 * 32 + hb) * KCt + kcS) * 512 + sub * 128 + c16 * 8;
    size_t bb3 = ((size_t)(3 * 32 + hb) * KCt + kcS) * 512 + sub * 128 + c16 * 8;
    const ushort* ph0 = Bhi + bb0; const ushort* pl0 = Blo + bb0;
    const ushort* ph1 = Bhi + bb1; const ushort* pl1 = Blo + bb1;
    const ushort* ph2 = Bhi + bb2; const ushort* pl2 = Blo + bb2;
    const ushort* ph3 = Bhi + bb3; const ushort* pl3 = Blo + bb3;

#define DO_CHUNK(PAH, PAL)                                                    \
    {                                                                         \
        bf16x8 ahi = *(const bf16x8*)(PAH);                                   \
        bf16x8 alo = *(const bf16x8*)(PAL);                                   \
        bf16x8 b0h = *(const bf16x8*)ph0; bf16x8 b0l = *(const bf16x8*)pl0;   \
        bf16x8 b1h = *(const bf16x8*)ph1; bf16x8 b1l = *(const bf16x8*)pl1;   \
        bf16x8 b2h = *(const bf16x8*)ph2; bf16x8 b2l = *(const bf16x8*)pl2;   \
        bf16x8 b3h = *(const bf16x8*)ph3; bf16x8 b3l = *(const bf16x8*)pl3;   \
        acc0 = __builtin_amdgcn_mfma_f32_16x16x32_bf16(ahi, b0h, acc0, 0, 0, 0); \
        acc1 = __builtin_amdgcn_mfma_f32_16x16x32_bf16(ahi, b1h, acc1, 0, 0, 0); \
        acc2 = __builtin_amdgcn_mfma_f32_16x16x32_bf16(ahi, b2h, acc2, 0, 0, 0); \
        acc3 = __builtin_amdgcn_mfma_f32_16x16x32_bf16(ahi, b3h, acc3, 0, 0, 0); \
        acc0 = __builtin_amdgcn_mfma_f32_16x16x32_bf16(ahi, b0l, acc0, 0, 0, 0); \
        acc1 = __builtin_amdgcn_mfma_f32_16x16x32_bf16(ahi, b1l, acc1, 0, 0, 0); \
        acc2 = __builtin_amdgcn_mfma_f32_16x16x32_bf16(ahi, b2l, acc2, 0, 0, 0); \
        acc3 = __builtin_amdgcn_mfma_f32_16x16x32_bf16(ahi, b3l, acc3, 0, 0, 0); \
        acc0 = __builtin_amdgcn_mfma_f32_16x16x32_bf16(alo, b0h, acc0, 0, 0, 0); \
        acc1 = __builtin_amdgcn_mfma_f32_16x16x32_bf16(alo, b1h, acc1, 0, 0, 0); \
        acc2 = __builtin_amdgcn_mfma_f32_16x16x32_bf16(alo, b2h, acc2, 0, 0, 0); \
        acc3 = __builtin_amdgcn_mfma_f32_16x16x32_bf16(alo, b3h, acc3, 0, 0, 0); \
        ph0 += 512; pl0 += 512; ph1 += 512; pl1 += 512;                       \
        ph2 += 512; pl2 += 512; ph3 += 512; pl3 += 512;                       \
    }

    // segment 1 (A1)
    int s1end = kcE < KCseg1 ? kcE : KCseg1;
    if (kcS < KCseg1) {
        const ushort* pa_h = Ahi1 + ((size_t)kcS * 4 + sub) * 4096 + arow * 8;
        const ushort* pa_l = Alo1 + ((size_t)kcS * 4 + sub) * 4096 + arow * 8;
#pragma unroll 2
        for (int kc = kcS; kc < s1end; ++kc) {
            DO_CHUNK(pa_h, pa_l);
            pa_h += 16384; pa_l += 16384;
        }
    }
    // segment 2 (A2)
    int s2start = kcS > KCseg1 ? kcS : KCseg1;
    if (kcE > KCseg1) {
        const ushort* pa_h = Ahi2 + ((size_t)(s2start - KCseg1) * 4 + sub) * 4096 + arow * 8;
        const ushort* pa_l = Alo2 + ((size_t)(s2start - KCseg1) * 4 + sub) * 4096 + arow * 8;
#pragma unroll 2
        for (int kc = s2start; kc < kcE; ++kc) {
            DO_CHUNK(pa_h, pa_l);
            pa_h += 16384; pa_l += 16384;
        }
    }
#undef DO_CHUNK

    // ---- K-split reduce + fused cell epilogue ----
    if (ks == 1) {
        *(f32x4*)&red[wrow][0][l][0] = acc0;
        *(f32x4*)&red[wrow][1][l][0] = acc1;
        *(f32x4*)&red[wrow][2][l][0] = acc2;
        *(f32x4*)&red[wrow][3][l][0] = acc3;
    }
    __syncthreads();
    if (ks == 0) {
        acc0 += *(f32x4*)&red[wrow][0][l][0];
        acc1 += *(f32x4*)&red[wrow][1][l][0];
        acc2 += *(f32x4*)&red[wrow][2][l][0];
        acc3 += *(f32x4*)&red[wrow][3][l][0];
        const int hc = hb * 16 + c16;
        const float bI = bias[hc];
        const float bF = bias[H + hc];
        const float bG = bias[2 * H + hc];
        const float bO = bias[3 * H + hc];
#pragma unroll
        for (int reg = 0; reg < 4; ++reg) {
            const int row = rowbase + sub * 4 + reg;  // C layout: row=(l>>4)*4+reg
            float zi = acc0[reg] + bI;
            float zf = acc1[reg] + bF;
            float zg = acc2[reg] + bG;
            float zo = acc3[reg] + bO;
            float co = cst[(size_t)row * H + hc];
            float cn = sigm(zf) * co + sigm(zi) * tanhf(zg);
            cst[(size_t)row * H + hc] = cn;
            float hn = sigm(zo) * tanhf(cn);
            if (h_f32) h_f32[(size_t)row * H + hc] = hn;
            ushort hib = f2bf(hn);
            size_t po = ((size_t)(hc >> 3) * 512 + row) * 8 + (hc & 7);
            h_hi[po] = hib;
            h_lo[po] = f2bf(hn - bf2f(hib));
        }
    }
}

// ---------------------------------------------------------------------------
// pred = h1_prev @ W + b (fp32, straight into prediction output row t-1),
// cur = where(x_t == MISSING, pred, x_t) written as packed hi/lo A-fragments.
// ---------------------------------------------------------------------------
__global__ __launch_bounds__(256) void pred_impute(
    const float* __restrict__ h1, const float* __restrict__ W,
    const float* __restrict__ bvec, const float* __restrict__ x_t,
    float* __restrict__ pred_out, ushort* __restrict__ curhi,
    ushort* __restrict__ curlo) {
    __shared__ float h1s[4 * H];
    const int tid = threadIdx.x;
    const int rowbase = blockIdx.x * 4;
    const float4* src = (const float4*)(h1 + (size_t)rowbase * H);
    float4* dst = (float4*)h1s;
    dst[tid] = src[tid];
    dst[tid + 256] = src[tid + 256];
    __syncthreads();

    const int r = tid >> 6;
    const int c = tid & 63;
    const float* hr = h1s + r * H;
    float acc = 0.f;
#pragma unroll 4
    for (int k = 0; k < H; k += 4) {
        float4 hv = *(const float4*)&hr[k];
        acc += hv.x * W[(k + 0) * D + c];
        acc += hv.y * W[(k + 1) * D + c];
        acc += hv.z * W[(k + 2) * D + c];
        acc += hv.w * W[(k + 3) * D + c];
    }
    acc += bvec[c];
    const int row = rowbase + r;
    pred_out[(size_t)row * PRED_ROW + c] = acc;
    float xv = x_t[(size_t)row * (T * D) + c];
    float cur = (xv == MISSING_V) ? acc : xv;
    ushort hib = f2bf(cur);
    size_t po = ((size_t)(c >> 3) * 512 + row) * 8 + (c & 7);
    curhi[po] = hib;
    curlo[po] = f2bf(cur - bf2f(hib));
}

// ---------------------------------------------------------------------------
// Fused: M output copy + masked-squared-error reduction into *accum.
// ---------------------------------------------------------------------------
__global__ __launch_bounds__(256) void pred_loss_reduce(
    const float* __restrict__ pred, const float* __restrict__ targ,
    const float* __restrict__ mask, float* __restrict__ Mout,
    float* __restrict__ accum) {
    const int n4 = PRED_ELEMS / 4;
    float part = 0.f;
    for (int i = blockIdx.x * blockDim.x + threadIdx.x; i < n4;
         i += gridDim.x * blockDim.x) {
        float4 p = ((const float4*)pred)[i];
        float4 t = ((const float4*)targ)[i];
        float4 m = ((const float4*)mask)[i];
        ((float4*)Mout)[i] = m;
        float dx = (t.x - p.x) * m.x;
        float dy = (t.y - p.y) * m.y;
        float dz = (t.z - p.z) * m.z;
        float dw = (t.w - p.w) * m.w;
        part += dx * dx + dy * dy + dz * dz + dw * dw;
    }
#pragma unroll
    for (int off = 32; off > 0; off >>= 1) part += __shfl_down(part, off, 64);
    __shared__ float wsum[4];
    int lane = threadIdx.x & 63, wid = threadIdx.x >> 6;
    if (lane == 0) wsum[wid] = part;
    __syncthreads();
    if (threadIdx.x == 0)
        atomicAdd(accum, wsum[0] + wsum[1] + wsum[2] + wsum[3]);
}

// ---------------------------------------------------------------------------
// Final: logits = h1_last @ Wc + bc; log-softmax loss; accuracy.
// ---------------------------------------------------------------------------
__global__ __launch_bounds__(64) void final_loss(
    const float* __restrict__ h1, const float* __restrict__ Wc,
    const float* __restrict__ bc, const float* __restrict__ label,
    const float* __restrict__ lp_accum, float* __restrict__ loss,
    float* __restrict__ acc_out) {
    const int b = blockIdx.x;
    const int lane = threadIdx.x;
    float partial[NC];
#pragma unroll
    for (int c = 0; c < NC; ++c) partial[c] = 0.f;
    for (int k = lane; k < H; k += 64) {
        float hv = h1[(size_t)b * H + k];
#pragma unroll
        for (int c = 0; c < NC; ++c) partial[c] += hv * Wc[k * NC + c];
    }
    float logits[NC];
#pragma unroll
    for (int c = 0; c < NC; ++c) {
        float v = partial[c];
#pragma unroll
        for (int off = 32; off > 0; off >>= 1) v += __shfl_down(v, off, 64);
        logits[c] = v + bc[c];
    }
    if (lane == 0) {
        float mx = logits[0];
#pragma unroll
        for (int c = 1; c < NC; ++c) mx = fmaxf(mx, logits[c]);
        float se = 0.f;
#pragma unroll
        for (int c = 0; c < NC; ++c) se += expf(logits[c] - mx);
        float lse = logf(se);
        float lcls = 0.f;
        int am_p = 0, am_l = 0;
        float bp = logits[0], bl = label[(size_t)b * NC];
#pragma unroll
        for (int c = 0; c < NC; ++c) {
            float lt = label[(size_t)b * NC + c];
            lcls -= lt * (logits[c] - mx - lse);
            if (c > 0) {
                if (logits[c] > bp) { bp = logits[c]; am_p = c; }
                if (lt > bl) { bl = lt; am_l = c; }
            }
        }
        float lp = lp_accum[0] * (1.0f / (float)PRED_ELEMS) * (1.0f / (float)B);
        loss[b] = lcls + lp;
        acc_out[b] = (am_p == am_l) ? 1.f : 0.f;
    }
}

// ---------------------------------------------------------------------------
extern "C" void kernel_launch(void* const* d_in, const int* in_sizes, int n_in,
                              void* d_out, int out_size, void* d_ws,
                              size_t ws_size, hipStream_t stream) {
    const float* inputs  = (const float*)d_in[0];
    const float* ptarget = (const float*)d_in[1];
    const float* mask    = (const float*)d_in[2];
    const float* label   = (const float*)d_in[3];
    const float* W       = (const float*)d_in[4];
    const float* bvec    = (const float*)d_in[5];
    const float* k0      = (const float*)d_in[6];
    const float* r0      = (const float*)d_in[7];
    const float* b0      = (const float*)d_in[8];
    const float* k1      = (const float*)d_in[9];
    const float* r1      = (const float*)d_in[10];
    const float* b1      = (const float*)d_in[11];
    const float* Wc      = (const float*)d_in[12];
    const float* bc      = (const float*)d_in[13];

    float* out = (float*)d_out;
    float* loss    = out;
    float* predout = out + B;
    float* Mout    = out + B + PRED_ELEMS;
    float* accout  = out + B + 2 * (size_t)PRED_ELEMS;

    // ---- ws layout (bytes; every buffer 16B-aligned) ----
    char* w = (char*)d_ws;
    // zero region: c0, c1, h0hiA, h0loA, h1hiA, h1loA, lp  (contiguous)
    float*  c0    = (float*)w;              w += (size_t)BH * 4;       // 1 MB
    float*  c1    = (float*)w;              w += (size_t)BH * 4;       // 1 MB
    ushort* h0hiA = (ushort*)w;             w += (size_t)BH * 2;
    ushort* h0loA = (ushort*)w;             w += (size_t)BH * 2;
    ushort* h1hiA = (ushort*)w;             w += (size_t)BH * 2;
    ushort* h1loA = (ushort*)w;             w += (size_t)BH * 2;
    float*  lp    = (float*)w;              w += 16;
    const int zero_n4 = (int)((2 * (size_t)BH * 4 + 4 * (size_t)BH * 2 + 16) / 16);
    // rest
    float*  h1f32 = (float*)w;              w += (size_t)BH * 4;
    ushort* h0hiB = (ushort*)w;             w += (size_t)BH * 2;
    ushort* h0loB = (ushort*)w;             w += (size_t)BH * 2;
    ushort* h1hiB = (ushort*)w;             w += (size_t)BH * 2;
    ushort* h1loB = (ushort*)w;             w += (size_t)BH * 2;
    ushort* curhi = (ushort*)w;             w += (size_t)B * D * 2;
    ushort* curlo = (ushort*)w;             w += (size_t)B * D * 2;
    ushort* x0hi  = (ushort*)w;             w += (size_t)B * D * 2;
    ushort* x0lo  = (ushort*)w;             w += (size_t)B * D * 2;
    ushort* Bhi0  = (ushort*)w;             w += (size_t)K0TOT * FOURH * 2;
    ushort* Blo0  = (ushort*)w;             w += (size_t)K0TOT * FOURH * 2;
    ushort* Bhi1  = (ushort*)w;             w += (size_t)K1TOT * FOURH * 2;
    ushort* Blo1  = (ushort*)w;             w += (size_t)K1TOT * FOURH * 2;

    pack_weights<<<2048, 256, 0, stream>>>(k0, r0, k1, r1, Bhi0, Blo0, Bhi1, Blo1);
    init_zero<<<512, 256, 0, stream>>>((float4*)d_ws, zero_n4);
    pack_x0<<<128, 256, 0, stream>>>(inputs, x0hi, x0lo);

    // ping-pong h packs
    ushort *h0rh = h0hiA, *h0rl = h0loA, *h0wh = h0hiB, *h0wl = h0loB;
    ushort *h1rh = h1hiA, *h1rl = h1loA, *h1wh = h1hiB, *h1wl = h1loB;

    // ---- t = 0: A1 = x0 (raw), A2 = h (zeros) ----
    gemm_cell_mfma<<<256, 512, 0, stream>>>(x0hi, x0lo, 2, h0rh, h0rl,
                                            Bhi0, Blo0, KC0, KC0 / 2, b0, c0,
                                            h0wh, h0wl, nullptr);
    gemm_cell_mfma<<<256, 512, 0, stream>>>(h0wh, h0wl, 16, h1rh, h1rl,
                                            Bhi1, Blo1, KC1, KC1 / 2, b1, c1,
                                            h1wh, h1wl, h1f32);
    { ushort* t;
      t = h0rh; h0rh = h0wh; h0wh = t;  t = h0rl; h0rl = h0wl; h0wl = t;
      t = h1rh; h1rh = h1wh; h1wh = t;  t = h1rl; h1rl = h1wl; h1wl = t; }

    // ---- t = 1 .. 127 ----
    for (int t = 1; t < T; ++t) {
        pred_impute<<<B / 4, 256, 0, stream>>>(h1f32, W, bvec, inputs + t * D,
                                               predout + (size_t)(t - 1) * D,
                                               curhi, curlo);
        gemm_cell_mfma<<<256, 512, 0, stream>>>(curhi, curlo, 2, h0rh, h0rl,
                                                Bhi0, Blo0, KC0, KC0 / 2, b0, c0,
                                                h0wh, h0wl, nullptr);
        gemm_cell_mfma<<<256, 512, 0, stream>>>(h0wh, h0wl, 16, h1rh, h1rl,
                                                Bhi1, Blo1, KC1, KC1 / 2, b1, c1,
                                                h1wh, h1wl, h1f32);
        ushort* tt;
        tt = h0rh; h0rh = h0wh; h0wh = tt;  tt = h0rl; h0rl = h0wl; h0wl = tt;
        tt = h1rh; h1rh = h1wh; h1wh = tt;  tt = h1rl; h1rl = h1wl; h1wl = tt;
    }

    // ---- epilogue ----
    pred_loss_reduce<<<1024, 256, 0, stream>>>(predout, ptarget, mask, Mout, lp);
    final_loss<<<B, 64, 0, stream>>>(h1f32, Wc, bc, label, lp, loss, accout);
}